// Round 13
// baseline (811.664 us; speedup 1.0000x reference)
//
#include <hip/hip_runtime.h>

typedef __attribute__((ext_vector_type(4))) float f32x4;
typedef __attribute__((ext_vector_type(8))) short bf16x8;
typedef __attribute__((ext_vector_type(2))) unsigned int u32x2;

#define NHEAD 6

__device__ __forceinline__ unsigned short f2bf(float f){
  union{float f;unsigned int u;}c; c.f=f;
  unsigned int x=c.u;
  return (unsigned short)((x + 0x7FFFu + ((x>>16)&1u)) >> 16);
}
__device__ __forceinline__ unsigned int cvtpk(float a, float b){
  unsigned int r;
  asm("v_cvt_pk_bf16_f32 %0, %1, %2" : "=v"(r) : "v"(a), "v"(b));
  return r;
}

// ---------------- weight cast+transpose: wt[n*K+k] = bf16(w[k*N+n]) ----------------
__global__ void wt_kernel(const float* __restrict__ w, unsigned short* __restrict__ wt,
                          int K, int N){
  int idx = blockIdx.x*256 + threadIdx.x;
  if (idx >= K*N) return;
  int k = idx / N, n = idx - k*N;
  wt[(size_t)n*K + k] = f2bf(w[idx]);
}

// ---------------- LayerNorm (+optional shift+window-partition), f32 in -> bf16 out ----
template<int SHIFT>
__global__ __launch_bounds__(256) void ln_kernel(const float* __restrict__ x,
    const float* __restrict__ gw, const float* __restrict__ bw,
    unsigned short* __restrict__ out){
  int tok  = blockIdx.x*4 + (threadIdx.x>>6);
  int lane = threadIdx.x & 63;
  const float* row = x + (size_t)tok*192;
  float4 v = make_float4(0.f,0.f,0.f,0.f);
  if (lane < 48) v = *(const float4*)(row + lane*4);
  float s  = v.x+v.y+v.z+v.w;
  float s2 = v.x*v.x+v.y*v.y+v.z*v.z+v.w*v.w;
  #pragma unroll
  for (int off=32; off; off>>=1){ s += __shfl_xor(s,off); s2 += __shfl_xor(s2,off); }
  float mu = s*(1.f/192.f);
  float rs = rsqrtf(s2*(1.f/192.f) - mu*mu + 1e-5f);
  size_t otok;
  if (SHIFT){
    int b = tok/3136; int hw = tok - b*3136; int h = hw/56; int w = hw - h*56;
    int hs = h-3; if (hs<0) hs += 56;
    int wsh = w-3; if (wsh<0) wsh += 56;
    int wr = hs/7, r = hs - wr*7, wc = wsh/7, c = wsh - wc*7;
    otok = ((size_t)b*64 + wr*8 + wc)*49 + r*7 + c;
  } else {
    otok = (size_t)tok;
  }
  if (lane < 48){
    int cb = lane*4;
    float4 g4 = *(const float4*)(gw + cb);
    float4 b4 = *(const float4*)(bw + cb);
    u32x2 o;
    o.x = cvtpk((v.x-mu)*rs*g4.x + b4.x, (v.y-mu)*rs*g4.y + b4.y);
    o.y = cvtpk((v.z-mu)*rs*g4.z + b4.z, (v.w-mu)*rs*g4.w + b4.w);
    *(u32x2*)(out + otok*192 + cb) = o;
  }
}

enum { EPI_PROJ=1, EPI_GELU=2, EPI_FINAL=3 };

// gelu(v) = v * sigmoid(v*(1.59576912 + 0.07135481 v^2))
__device__ __forceinline__ float gelu_fast(float v){
  float t = v*(1.59576912f + 0.07135481f*v*v);
  float e = __expf(-t);
  return v/(1.f + e);
}

__device__ __forceinline__ size_t proj_rowbase(int grow){
  int winr = grow/49; int nn = grow - winr*49;
  int b  = winr>>6; int wi = winr&63; int wr_ = wi>>3; int wc_ = wi&7;
  int r7 = nn/7;  int c7 = nn - r7*7;
  int h = wr_*7 + r7 + 3; if (h>=56) h-=56;
  int w = wc_*7 + c7 + 3; if (w>=56) w-=56;
  return (((size_t)b*3136) + h*56 + w)*192;
}

// ---------------- GEMM: 256x64 tile, BK=64, 8 waves; R10 epilogues ------------------
template<int EPI>
__global__ __launch_bounds__(512) void gemm_k(
    const unsigned short* __restrict__ A,
    const unsigned short* __restrict__ BT,
    const float* __restrict__ bias,
    const float* __restrict__ res,
    void* __restrict__ Cout,
    int M, int N, int Nb, int K)
{
  __shared__ unsigned short lA[256*64];
  __shared__ unsigned short lB[64*64];
  const int tid  = threadIdx.x;
  const int wave = tid>>6, lane = tid&63;
  const int wm = wave>>1, wn = wave&1;
  const int lr = lane&15, lh = lane>>4;

  int bid = blockIdx.x;
  int yb = bid/(8*Nb); int rr = bid - yb*8*Nb; int xq = rr>>3; int y8 = rr&7;
  const int m0 = (yb*8 + y8)*256, n0 = xq*64;

  f32x4 zero = {0.f,0.f,0.f,0.f};
  f32x4 acc[4][2];
  #pragma unroll
  for (int i=0;i<4;i++){ acc[i][0]=zero; acc[i][1]=zero; }

  const int row8 = tid>>3;
  const int csw  = ((tid&7) ^ (row8&7))*8;
  const unsigned short* Ag = A  + (size_t)(m0 + row8)*K + csw;
  const unsigned short* Bg = BT + (size_t)(n0 + row8)*K + csw;

  for (int kt=0; kt<K; kt+=64){
    __syncthreads();
    #pragma unroll
    for (int i=0;i<4;i++){
      __builtin_amdgcn_global_load_lds(
        (const __attribute__((address_space(1))) void*)(Ag + (size_t)i*64*K + kt),
        (__attribute__((address_space(3))) void*)(lA + i*4096 + wave*512),
        16, 0, 0);
    }
    __builtin_amdgcn_global_load_lds(
      (const __attribute__((address_space(1))) void*)(Bg + kt),
      (__attribute__((address_space(3))) void*)(lB + wave*512),
      16, 0, 0);
    __syncthreads();

    bf16x8 af[4][2], bfv[2][2];
    #pragma unroll
    for (int mi=0;mi<4;mi++)
      #pragma unroll
      for (int ks=0;ks<2;ks++){
        int arow = wm*64+mi*16+lr;
        af[mi][ks] = *(const bf16x8*)&lA[arow*64 + (((ks*4+lh) ^ (lr&7))*8)];
      }
    #pragma unroll
    for (int ni=0;ni<2;ni++)
      #pragma unroll
      for (int ks=0;ks<2;ks++){
        int brow = wn*32+ni*16+lr;
        bfv[ni][ks] = *(const bf16x8*)&lB[brow*64 + (((ks*4+lh) ^ (lr&7))*8)];
      }
    #pragma unroll
    for (int mi=0;mi<4;mi++)
      #pragma unroll
      for (int ni=0;ni<2;ni++)
        #pragma unroll
        for (int ks=0;ks<2;ks++)
          acc[mi][ni] = __builtin_amdgcn_mfma_f32_16x16x32_bf16(
              bfv[ni][ks], af[mi][ks], acc[mi][ni], 0,0,0);
  }

  if (EPI == EPI_GELU){
    // bf16 tile [256][64] = 32KB in lA; 16B-chunk XOR swizzle (^ row&7)
    __syncthreads();
    #pragma unroll
    for (int mi=0;mi<4;mi++){
      int row = wm*64 + mi*16 + lr;
      #pragma unroll
      for (int ni=0;ni<2;ni++){
        int colb = n0 + wn*32 + ni*16 + lh*4;
        float4 bv4 = *(const float4*)(bias + colb);
        float v0 = acc[mi][ni][0] + bv4.x;
        float v1 = acc[mi][ni][1] + bv4.y;
        float v2 = acc[mi][ni][2] + bv4.z;
        float v3 = acc[mi][ni][3] + bv4.w;
        u32x2 st;
        st.x = cvtpk(gelu_fast(v0), gelu_fast(v1));
        st.y = cvtpk(gelu_fast(v2), gelu_fast(v3));
        int c16 = wn*4 + ni*2 + (lh>>1);
        int byte = row*128 + ((c16 ^ (row&7))*16) + (lh&1)*8;
        *(u32x2*)((char*)lA + byte) = st;
      }
    }
    __syncthreads();
    #pragma unroll
    for (int rnd=0; rnd<4; ++rnd){
      int row = rnd*64 + (tid>>3);
      int chunk = tid&7;
      uint4 vv = *(const uint4*)((const char*)lA + row*128 + ((chunk ^ (row&7))*16));
      int grow = m0 + row;
      *(uint4*)((unsigned short*)Cout + (size_t)grow*N + n0 + chunk*8) = vv;
    }
  } else {
    // f32 tile [128][64] = 32KB; two halves; 16B-chunk swizzle (^ row&15)
    float* Tf = (float*)lA;
    #pragma unroll
    for (int h=0; h<2; ++h){
      __syncthreads();
      if ((wave>>2) == h){
        #pragma unroll
        for (int mi=0;mi<4;mi++){
          int lrow = (wm&1)*64 + mi*16 + lr;
          #pragma unroll
          for (int ni=0;ni<2;ni++){
            int colb = n0 + wn*32 + ni*16 + lh*4;
            float4 bv4 = *(const float4*)(bias + colb);
            float4 val = make_float4(acc[mi][ni][0]+bv4.x, acc[mi][ni][1]+bv4.y,
                                     acc[mi][ni][2]+bv4.z, acc[mi][ni][3]+bv4.w);
            int c4 = wn*8 + ni*4 + lh;
            *(float4*)&Tf[lrow*64 + ((c4 ^ (lrow&15))*4)] = val;
          }
        }
      }
      __syncthreads();
      #pragma unroll
      for (int rnd=0; rnd<4; ++rnd){
        int lrow = rnd*32 + (tid>>4);
        int chunk = tid&15;
        float4 v = *(const float4*)&Tf[lrow*64 + ((chunk ^ (lrow&15))*4)];
        int grow = m0 + h*128 + lrow;
        size_t base;
        if (EPI == EPI_FINAL) base = (size_t)grow*N + n0 + chunk*4;
        else                  base = proj_rowbase(grow) + n0 + chunk*4;
        float4 rv = *(const float4*)(res + base);
        *(float4*)((float*)Cout + base) =
            make_float4(rv.x+v.x, rv.y+v.y, rv.z+v.z, rv.w+v.w);
      }
    }
  }
}

// ---------------- fused QKV gemm + attention: one block per window ------------------
// 384 threads (6 waves). Phase 1: stage xw 64x192 (rows>=49 zeroed, chunk-swizzled).
// Phase 2: wave w computes QKV cols [w*96,(w+1)*96) (M=64,K=192,144 MFMA), weights
// read straight from L2 to registers, NO K-loop barriers. Epilogue writes Q/K (+bias,
// attn-ready swizzle) and V transposed into per-head LDS slots. Phase 3: wave h does
// attention for head h (R10-verified math), writes 49x32 output slice.
__global__ __launch_bounds__(384) void qkv_attn(
    const unsigned short* __restrict__ xw,
    const unsigned short* __restrict__ qkvT,
    const float* __restrict__ bias,
    unsigned short* __restrict__ aout)
{
  __shared__ __align__(16) unsigned short smem[36864]; // 72KB: QK 6x4096 | Vt 6x2048
  const int tid  = threadIdx.x;
  const int wave = tid>>6, lane = tid&63;
  const int lr = lane&15, lh = lane>>4;
  const int win = blockIdx.x;
  unsigned short* xwl = smem;                 // 64x192 overlay (dead before epilogue)
  const size_t xbase = (size_t)win*49*192;

  // ---- phase 1: stage xw, swizzle chunk c -> c ^ (row&7) ----
  #pragma unroll
  for (int p=0; p<4; ++p){
    int c = p*384 + tid;                      // 0..1535
    int row = c/24, col = c - row*24;
    unsigned short* dst = &xwl[row*192 + ((col ^ (row&7))*8)];
    if (row < 49){
      *(uint4*)dst = *(const uint4*)(xw + xbase + (size_t)row*192 + col*8);
    } else {
      *(uint4*)dst = make_uint4(0,0,0,0);
    }
  }
  __syncthreads();

  // ---- phase 2: QKV gemm ----
  f32x4 zero = {0.f,0.f,0.f,0.f};
  f32x4 acc[4][6];
  #pragma unroll
  for (int i=0;i<4;i++)
    #pragma unroll
    for (int j=0;j<6;j++) acc[i][j]=zero;
  const int ncol0 = wave*96;

  #pragma unroll
  for (int kk=0; kk<6; ++kk){
    bf16x8 af[4];
    #pragma unroll
    for (int mi=0;mi<4;mi++)
      af[mi] = *(const bf16x8*)&xwl[(mi*16+lr)*192 + (((kk*4+lh) ^ (lr&7))*8)];
    bf16x8 bfv[6];
    #pragma unroll
    for (int j=0;j<6;j++)
      bfv[j] = *(const bf16x8*)(qkvT + (size_t)(ncol0 + j*16 + lr)*192 + kk*32 + lh*8);
    #pragma unroll
    for (int mi=0;mi<4;mi++)
      #pragma unroll
      for (int j=0;j<6;j++)
        acc[mi][j] = __builtin_amdgcn_mfma_f32_16x16x32_bf16(
            bfv[j], af[mi], acc[mi][j], 0,0,0);
  }
  __syncthreads();   // all xw reads done; epilogue overlays

  // ---- phase 2 epilogue: scatter into attn-ready LDS slots ----
  const int which = wave>>1;                // 0=Q 1=K 2=V
  #pragma unroll
  for (int j=0;j<6;j++){
    int unit = j>>1, ni_u = j&1;
    int head = (wave&1)*3 + unit;
    int d0 = ni_u*16 + lh*4;
    float4 bb = *(const float4*)(bias + which*192 + head*32 + d0);
    #pragma unroll
    for (int mi=0;mi<4;mi++){
      int row = mi*16 + lr;
      float v0 = acc[mi][j][0]+bb.x, v1 = acc[mi][j][1]+bb.y;
      float v2 = acc[mi][j][2]+bb.z, v3 = acc[mi][j][3]+bb.w;
      if (which < 2){
        unsigned short* base = smem + head*4096 + which*2048;
        int blk = d0>>3;
        int sb = blk ^ (row&3) ^ ((row>>2)&3);
        int addr = row*32 + sb*8 + (d0&7);
        u32x2 st; st.x = cvtpk(v0,v1); st.y = cvtpk(v2,v3);
        *(u32x2*)(base + addr) = st;
      } else {
        unsigned short* vt = smem + 24576 + head*2048;
        int rb = row>>3, re = row&7;
        vt[(d0+0)*64 + ((rb ^ ((d0+0)&7))*8) + re] = f2bf(v0);
        vt[(d0+1)*64 + ((rb ^ ((d0+1)&7))*8) + re] = f2bf(v1);
        vt[(d0+2)*64 + ((rb ^ ((d0+2)&7))*8) + re] = f2bf(v2);
        vt[(d0+3)*64 + ((rb ^ ((d0+3)&7))*8) + re] = f2bf(v3);
      }
    }
  }
  __syncthreads();

  // ---- phase 3: attention, head = wave ----
  const int head = wave;
  unsigned short* Q  = smem + head*4096;
  unsigned short* Kl = Q + 2048;
  unsigned short* P  = Q;                    // overlay after frag reads
  unsigned short* Vt = smem + 24576 + head*2048;

  bf16x8 kf[4], qf[4];
  #pragma unroll
  for (int t=0;t<4;t++){
    int row = t*16 + lr;
    int off = row*32 + ((lh ^ (row&3) ^ ((row>>2)&3))*8);
    kf[t] = *(const bf16x8*)&Kl[off];
    qf[t] = *(const bf16x8*)&Q[off];
  }

  f32x4 S[4][4];
  #pragma unroll
  for (int mi=0;mi<4;mi++)
    #pragma unroll
    for (int ni=0;ni<4;ni++)
      S[mi][ni] = __builtin_amdgcn_mfma_f32_16x16x32_bf16(kf[mi], qf[ni], zero, 0,0,0);

  const int wi = win & 63, wr = wi>>3, wc = wi&7;
  const bool hasmask = (wr==7) || (wc==7);
  const float scale = 0.17677669529663687f;

  #pragma unroll
  for (int ni=0;ni<4;ni++){
    int q = ni*16 + lr;
    int idq = 0;
    if (hasmask){
      int qr = q/7, qc = q - qr*7;
      int ih = (wr==7) ? ((qr>=4)?2:1) : 0;
      int iw = (wc==7) ? ((qc>=4)?2:1) : 0;
      idq = ih*3 + iw;
    }
    #pragma unroll
    for (int mi=0;mi<4;mi++){
      #pragma unroll
      for (int r=0;r<4;r++){
        int key = mi*16 + lh*4 + r;
        float s;
        if (key >= 49) s = -1e30f;
        else {
          float add = 0.f;
          if (hasmask){
            int kr = key/7, kc = key - kr*7;
            int ih = (wr==7) ? ((kr>=4)?2:1) : 0;
            int iw = (wc==7) ? ((kc>=4)?2:1) : 0;
            add = ((ih*3+iw) == idq) ? 0.f : -100.f;
          }
          s = S[mi][ni][r]*scale + add;
        }
        S[mi][ni][r] = s;
      }
    }
    float m = -1e30f;
    #pragma unroll
    for (int mi=0;mi<4;mi++)
      #pragma unroll
      for (int r=0;r<4;r++) m = fmaxf(m, S[mi][ni][r]);
    m = fmaxf(m, __shfl_xor(m, 16));
    m = fmaxf(m, __shfl_xor(m, 32));
    float sum = 0.f;
    #pragma unroll
    for (int mi=0;mi<4;mi++)
      #pragma unroll
      for (int r=0;r<4;r++){
        float p = __expf(S[mi][ni][r] - m);
        S[mi][ni][r] = p; sum += p;
      }
    sum += __shfl_xor(sum, 16);
    sum += __shfl_xor(sum, 32);
    float inv = 1.f/sum;
    #pragma unroll
    for (int mi=0;mi<4;mi++){
      int keyb = mi*16 + lh*4;
      int blk = keyb>>3, e0 = keyb&7;
      int addr = q*64 + ((blk ^ (q&7))*8) + e0;
      *(unsigned int*)&P[addr]   = cvtpk(S[mi][ni][0]*inv, S[mi][ni][1]*inv);
      *(unsigned int*)&P[addr+2] = cvtpk(S[mi][ni][2]*inv, S[mi][ni][3]*inv);
    }
  }

  bf16x8 vf[2][2];
  #pragma unroll
  for (int mt=0;mt<2;mt++)
    #pragma unroll
    for (int ks=0;ks<2;ks++){
      int row = mt*16 + lr;
      vf[mt][ks] = *(const bf16x8*)&Vt[row*64 + (((ks*4+lh) ^ (row&7))*8)];
    }
  f32x4 O[2][4];
  #pragma unroll
  for (int ni=0;ni<4;ni++){
    int q = ni*16 + lr;
    bf16x8 pf0 = *(const bf16x8*)&P[q*64 + (((0*4+lh) ^ (q&7))*8)];
    bf16x8 pf1 = *(const bf16x8*)&P[q*64 + (((1*4+lh) ^ (q&7))*8)];
    #pragma unroll
    for (int mt=0;mt<2;mt++){
      f32x4 t = __builtin_amdgcn_mfma_f32_16x16x32_bf16(vf[mt][0], pf0, zero, 0,0,0);
      O[mt][ni] = __builtin_amdgcn_mfma_f32_16x16x32_bf16(vf[mt][1], pf1, t, 0,0,0);
    }
  }

  #pragma unroll
  for (int ni=0;ni<4;ni++){
    int q = ni*16 + lr;
    if (q < 49){
      size_t ob = ((size_t)win*49 + q)*192 + head*32 + lh*4;
      #pragma unroll
      for (int mt=0;mt<2;mt++){
        u32x2 st;
        st.x = cvtpk(O[mt][ni][0], O[mt][ni][1]);
        st.y = cvtpk(O[mt][ni][2], O[mt][ni][3]);
        *(u32x2*)(aout + ob + mt*16) = st;
      }
    }
  }
}

// ---------------- launcher ----------------
extern "C" void kernel_launch(void* const* d_in, const int* in_sizes, int n_in,
                              void* d_out, int out_size, void* d_ws, size_t ws_size,
                              hipStream_t stream){
  (void)in_sizes; (void)n_in; (void)out_size; (void)ws_size;
  const float* x      = (const float*)d_in[0];
  const float* n1_g   = (const float*)d_in[1];
  const float* n1_b   = (const float*)d_in[2];
  const float* qkv_w  = (const float*)d_in[3];
  const float* qkv_b  = (const float*)d_in[4];
  const float* proj_w = (const float*)d_in[5];
  const float* proj_b = (const float*)d_in[6];
  const float* n2_g   = (const float*)d_in[7];
  const float* n2_b   = (const float*)d_in[8];
  const float* w1     = (const float*)d_in[9];
  const float* b1     = (const float*)d_in[10];
  const float* w2     = (const float*)d_in[11];
  const float* b2     = (const float*)d_in[12];

  char* ws = (char*)d_ws;
  unsigned short* qkvT = (unsigned short*)(ws + 0);          // 576*192 bf16
  unsigned short* projT= (unsigned short*)(ws + 221184);     // 192*192
  unsigned short* w1T  = (unsigned short*)(ws + 294912);     // 768*192
  unsigned short* w2T  = (unsigned short*)(ws + 589824);     // 192*768
  unsigned short* bufA = (unsigned short*)(ws + 884736);     // 200704*192 bf16 (xw / x2n)
  unsigned short* bufB = (unsigned short*)(ws + 77955072);   // attn-out, later h [200704*768]
  float*          x2   = (float*)        (ws + 386236416);   // 200704*192 f32
  float* out = (float*)d_out;
  const int M = 200704;

  wt_kernel<<<432,256,0,stream>>>(qkv_w, qkvT, 192, 576);
  wt_kernel<<<144,256,0,stream>>>(proj_w, projT, 192, 192);
  wt_kernel<<<576,256,0,stream>>>(w1,    w1T,  192, 768);
  wt_kernel<<<576,256,0,stream>>>(w2,    w2T,  768, 192);

  ln_kernel<1><<<50176,256,0,stream>>>(x, n1_g, n1_b, bufA);
  qkv_attn<<<4096,384,0,stream>>>(bufA, qkvT, qkv_b, bufB);
  gemm_k<EPI_PROJ ><<< 3*784, 512,0,stream>>>(bufB, projT, proj_b, x, x2, M, 192, 3, 192);
  ln_kernel<0><<<50176,256,0,stream>>>(x2, n2_g, n2_b, bufA);
  gemm_k<EPI_GELU ><<<12*784, 512,0,stream>>>(bufA, w1T, b1, nullptr, bufB, M, 768, 12, 192);
  gemm_k<EPI_FINAL><<< 3*784, 512,0,stream>>>(bufB, w2T, b2, x2, out, M, 192, 3, 768);
}